// Round 4
// baseline (1166.071 us; speedup 1.0000x reference)
//
#include <hip/hip_runtime.h>

// RWKV-6 style block on MI355X (gfx950).
// E=2048, H=32, S=64, L=1024, B=4.
// Round 9: WKV scan rebuilt around the LDS-pipe roofline (round-3 PMC model:
//          194us of pure DS issue). Lane now owns 8 i-rows (R/K = 1 ds_read_b128
//          each, W = 2), reduction is 3 stages with xor1/xor2 as DPP VALU adds
//          (quad_perm) and only xor4 on the LDS pipe. 512 blocks x 128 thr,
//          2 blocks/CU. GEMMs unchanged from round 8.

#define E     2048
#define LL    1024
#define HHH   32
#define SSS   64
#define NBL   4096      // B*L
#define NBLE  8388608   // B*L*E

typedef short bf16x8 __attribute__((ext_vector_type(8)));
typedef float f32x4  __attribute__((ext_vector_type(4)));
using u16 = unsigned short;

__device__ __forceinline__ u16 f2b(float f) {
    union { float f; unsigned int u; } c; c.f = f;
    unsigned int u = c.u;
    unsigned int r = (u + 0x7fffu + ((u >> 16) & 1u)) >> 16;
    return (u16)r;
}
__device__ __forceinline__ float b2f(u16 b) {
    union { unsigned int u; float f; } c; c.u = ((unsigned int)b) << 16; return c.f;
}

__device__ __forceinline__ float wave_sum(float v) {
#pragma unroll
    for (int m = 32; m >= 1; m >>= 1) v += __shfl_xor(v, m, 64);
    return v;
}

__device__ __forceinline__ void gl_lds16(const void* g, void* l) {
    __builtin_amdgcn_global_load_lds((const __attribute__((address_space(1))) unsigned int*)g,
                                     (__attribute__((address_space(3))) unsigned int*)l, 16, 0, 0);
}

// cross-lane add helpers: DPP (VALU pipe) for xor1/xor2, ds_swizzle for xor4
template <int CTRL>
__device__ __forceinline__ float dpp_mov(float v) {
    int s = __builtin_bit_cast(int, v);
    int r = __builtin_amdgcn_update_dpp(s, s, CTRL, 0xF, 0xF, false);
    return __builtin_bit_cast(float, r);
}
__device__ __forceinline__ float swz_xor4(float v) {
    int r = __builtin_amdgcn_ds_swizzle(__builtin_bit_cast(int, v), 0x101F);
    return __builtin_bit_cast(float, r);
}

// ---------------- elementwise / prep kernels ----------------

__global__ __launch_bounds__(256) void k_convert(const float* __restrict__ in,
                                                 u16* __restrict__ out, int n) {
    int i = (blockIdx.x * 256 + threadIdx.x) * 4;
    if (i >= n) return;
    float4 v = *reinterpret_cast<const float4*>(in + i);
    ushort4 o = make_ushort4(f2b(v.x), f2b(v.y), f2b(v.z), f2b(v.w));
    *reinterpret_cast<ushort4*>(out + i) = o;
}

// in (R,C) fp32 -> out (C,R) bf16
__global__ __launch_bounds__(256) void k_transpose(const float* __restrict__ in,
                                                   u16* __restrict__ out, int R, int C) {
    int i = blockIdx.x * 256 + threadIdx.x;
    if (i >= R * C) return;
    int r = i / C, c = i - r * C;
    out[c * R + r] = f2b(in[i]);
}

__global__ __launch_bounds__(256) void k_ln(const float* __restrict__ x,
                                            const float* __restrict__ w,
                                            const float* __restrict__ b,
                                            float* __restrict__ out) {
    int row = blockIdx.x, tid = threadIdx.x;
    const float* xr = x + (size_t)row * E + tid * 8;
    float4 v0 = *reinterpret_cast<const float4*>(xr);
    float4 v1 = *reinterpret_cast<const float4*>(xr + 4);
    float s = v0.x + v0.y + v0.z + v0.w + v1.x + v1.y + v1.z + v1.w;
    __shared__ float red[4];
    s = wave_sum(s);
    int wid = tid >> 6, lane = tid & 63;
    if (lane == 0) red[wid] = s;
    __syncthreads();
    float mean = (red[0] + red[1] + red[2] + red[3]) * (1.0f / E);
    __syncthreads();
    float q = 0.f;
    q += (v0.x - mean) * (v0.x - mean); q += (v0.y - mean) * (v0.y - mean);
    q += (v0.z - mean) * (v0.z - mean); q += (v0.w - mean) * (v0.w - mean);
    q += (v1.x - mean) * (v1.x - mean); q += (v1.y - mean) * (v1.y - mean);
    q += (v1.z - mean) * (v1.z - mean); q += (v1.w - mean) * (v1.w - mean);
    q = wave_sum(q);
    if (lane == 0) red[wid] = q;
    __syncthreads();
    float inv = rsqrtf((red[0] + red[1] + red[2] + red[3]) * (1.0f / E) + 1e-5f);
    int e = tid * 8;
    float4 w0 = *reinterpret_cast<const float4*>(w + e);
    float4 w1 = *reinterpret_cast<const float4*>(w + e + 4);
    float4 b0 = *reinterpret_cast<const float4*>(b + e);
    float4 b1 = *reinterpret_cast<const float4*>(b + e + 4);
    float4 o0, o1;
    o0.x = (v0.x - mean) * inv * w0.x + b0.x; o0.y = (v0.y - mean) * inv * w0.y + b0.y;
    o0.z = (v0.z - mean) * inv * w0.z + b0.z; o0.w = (v0.w - mean) * inv * w0.w + b0.w;
    o1.x = (v1.x - mean) * inv * w1.x + b1.x; o1.y = (v1.y - mean) * inv * w1.y + b1.y;
    o1.z = (v1.z - mean) * inv * w1.z + b1.z; o1.w = (v1.w - mean) * inv * w1.w + b1.w;
    float* op = out + (size_t)row * E + e;
    *reinterpret_cast<float4*>(op) = o0;
    *reinterpret_cast<float4*>(op + 4) = o1;
}

// mk = bf16(xa + sx*maa_x), sx recomputed inline (time-mix shift, state row 1)
__global__ __launch_bounds__(256) void k_mk(const float* __restrict__ xa,
                                            const float* __restrict__ state,
                                            const float* __restrict__ maa_x,
                                            u16* __restrict__ out) {
    int i = (blockIdx.x * 256 + threadIdx.x) * 4;
    if (i >= NBLE) return;
    int n = i >> 11, e = i & (E - 1);
    int l = n & (LL - 1), b = n >> 10;
    float4 cur = *reinterpret_cast<const float4*>(xa + i);
    float4 prev;
    if (l > 0) prev = *reinterpret_cast<const float4*>(xa + i - E);
    else       prev = *reinterpret_cast<const float4*>(state + (size_t)b * 66 * E + E + e);
    float4 m = *reinterpret_cast<const float4*>(maa_x + e);
    ushort4 o = make_ushort4(f2b(cur.x + (prev.x - cur.x) * m.x),
                             f2b(cur.y + (prev.y - cur.y) * m.y),
                             f2b(cur.z + (prev.z - cur.z) * m.z),
                             f2b(cur.w + (prev.w - cur.w) * m.w));
    *reinterpret_cast<ushort4*>(out + i) = o;
}

// channel-mix token shift (state row 0) + two mixes -> bf16
__global__ __launch_bounds__(256) void k_mix2(const float* __restrict__ xc,
                                              const float* __restrict__ state,
                                              const float* __restrict__ mk,
                                              const float* __restrict__ mr,
                                              u16* __restrict__ xk2,
                                              u16* __restrict__ xr2) {
    int i = (blockIdx.x * 256 + threadIdx.x) * 4;
    if (i >= NBLE) return;
    int n = i >> 11, e = i & (E - 1);
    int l = n & (LL - 1), b = n >> 10;
    float4 cur = *reinterpret_cast<const float4*>(xc + i);
    float4 prev;
    if (l > 0) prev = *reinterpret_cast<const float4*>(xc + i - E);
    else       prev = *reinterpret_cast<const float4*>(state + (size_t)b * 66 * E + e);
    float4 sx = make_float4(prev.x - cur.x, prev.y - cur.y, prev.z - cur.z, prev.w - cur.w);
    float4 k4 = *reinterpret_cast<const float4*>(mk + e);
    float4 r4 = *reinterpret_cast<const float4*>(mr + e);
    ushort4 ok = make_ushort4(f2b(cur.x + sx.x * k4.x), f2b(cur.y + sx.y * k4.y),
                              f2b(cur.z + sx.z * k4.z), f2b(cur.w + sx.w * k4.w));
    ushort4 orr = make_ushort4(f2b(cur.x + sx.x * r4.x), f2b(cur.y + sx.y * r4.y),
                               f2b(cur.z + sx.z * r4.z), f2b(cur.w + sx.w * r4.w));
    *reinterpret_cast<ushort4*>(xk2 + i) = ok;
    *reinterpret_cast<ushort4*>(xr2 + i) = orr;
}

// per-head groupnorm over S=64, *gn_w+gn_b, *g (bf16, in-place ok) -> bf16
__global__ __launch_bounds__(256) void k_gnorm(const float* __restrict__ wkv,
                                               const u16* __restrict__ g,
                                               const float* __restrict__ gw,
                                               const float* __restrict__ gb,
                                               u16* __restrict__ ogg) {
    int gidx = blockIdx.x * 4 + (threadIdx.x >> 6);
    int lane = threadIdx.x & 63;
    int n = gidx >> 5, h = gidx & 31;
    size_t base = (size_t)n * E + h * SSS;
    float v = wkv[base + lane];
    float mean = wave_sum(v) * (1.0f / SSS);
    float d = v - mean;
    float var = wave_sum(d * d) * (1.0f / SSS);
    float norm = d * rsqrtf(var + 1e-5f);
    int e = h * SSS + lane;
    float res = norm * gw[e] + gb[e];
    float gv = b2f(g[base + lane]);
    ogg[base + lane] = f2b(res * gv);
}

// ---------------- WKV sequential scan (LDS-pipe-minimized) ------------------
// grid = B*H*4 = 512 blocks of 128 (2 waves, 2 blocks/CU).  Block = (b,h,jq)
// with 16 j-columns; (b,h) fastest in blockIdx for XCD L2 sharing.
// Lane = (jl<<3)|ig: ig in LOW bits so the i-reduction runs xor1/xor2 as DPP
// quad_perm VALU adds (off the LDS pipe) and only xor4 as ds_swizzle.
// Lane owns 8 state rows -> R/K fragment = 1 ds_read_b128, W = 2.
// 16-timestep chunks staged via global_load_lds, double buffered.
#define CT 16

__global__ __launch_bounds__(128) void k_scan(const u16* __restrict__ Rb,
                                              const u16* __restrict__ Kb,
                                              const u16* __restrict__ Vb,
                                              const float* __restrict__ W,
                                              const float* __restrict__ state,
                                              const float* __restrict__ u,
                                              float* __restrict__ out) {
    __shared__ u16   ldsR[2][CT * 64];
    __shared__ u16   ldsK[2][CT * 64];
    __shared__ float ldsW[2][CT * 64];
    __shared__ u16   ldsV[2][CT * 16];
    const int blk = blockIdx.x;
    const int bh = blk & 127;            // (b,h) fastest
    const int jq = blk >> 7;             // 0..3  (16 j-columns each)
    const int b = bh >> 5, h = bh & 31;
    const int tid = threadIdx.x;         // 0..127
    const int wvid = tid >> 6;           // 0..1
    const int lane = tid & 63;
    const int ig = lane & 7;             // i-group (low bits -> DPP reduction)
    const int jl = lane >> 3;            // 0..7
    const int jv = wvid * 8 + jl;        // 0..15
    const int j  = jq * 16 + jv;
    const int i0 = ig * 8;               // 8 rows per lane
    float s[8], uu[8];
    const float* s0 = state + (size_t)b * 66 * E + 2 * E + h * (SSS * SSS);
#pragma unroll
    for (int r = 0; r < 8; r++) {
        s[r] = s0[(i0 + r) * SSS + j];
        uu[r] = u[h * SSS + i0 + r];
    }
    const size_t off0 = (size_t)b * LL * E + h * SSS;

    // staging: all 128 threads; R 2KB, K 2KB, W 4KB, V 0.5KB per chunk
    auto stage = [&](int c, int bufsel) {
        size_t base = off0 + (size_t)c * CT * E;
        const u16* gR = Rb + base + (size_t)(tid >> 3) * E + ((tid & 7) << 3);
        gl_lds16(gR, &ldsR[bufsel][tid * 8]);
        const u16* gK = Kb + base + (size_t)(tid >> 3) * E + ((tid & 7) << 3);
        gl_lds16(gK, &ldsK[bufsel][tid * 8]);
        const float* gW = W + base + (size_t)(tid >> 4) * E + ((tid & 15) << 2);
        gl_lds16(gW,         &ldsW[bufsel][tid * 4]);
        gl_lds16(gW + 8 * E, &ldsW[bufsel][512 + tid * 4]);
        if (tid < 32) {
            const u16* gV = Vb + base + (size_t)(tid >> 1) * E + jq * 16 + ((tid & 1) << 3);
            gl_lds16(gV, &ldsV[bufsel][tid * 8]);
        }
    };

    stage(0, 0);
    __syncthreads();
    int cur = 0;
    for (int c = 0; c < LL / CT; c++) {
        if (c + 1 < LL / CT) stage(c + 1, cur ^ 1);
        float accs[CT];
#pragma unroll
        for (int tt = 0; tt < CT; tt++) {
            bf16x8 rv = *reinterpret_cast<const bf16x8*>(&ldsR[cur][tt * 64 + i0]);
            bf16x8 kv = *reinterpret_cast<const bf16x8*>(&ldsK[cur][tt * 64 + i0]);
            float4  w0 = *reinterpret_cast<const float4*>(&ldsW[cur][tt * 64 + i0]);
            float4  w1 = *reinterpret_cast<const float4*>(&ldsW[cur][tt * 64 + i0 + 4]);
            float vj = b2f(ldsV[cur][tt * 16 + jv]);
            float acc = 0.f, a;
            a = b2f((u16)kv[0]) * vj; acc += b2f((u16)rv[0]) * fmaf(uu[0], a, s[0]); s[0] = fmaf(w0.x, s[0], a);
            a = b2f((u16)kv[1]) * vj; acc += b2f((u16)rv[1]) * fmaf(uu[1], a, s[1]); s[1] = fmaf(w0.y, s[1], a);
            a = b2f((u16)kv[2]) * vj; acc += b2f((u16)rv[2]) * fmaf(uu[2], a, s[2]); s[2] = fmaf(w0.z, s[2], a);
            a = b2f((u16)kv[3]) * vj; acc += b2f((u16)rv[3]) * fmaf(uu[3], a, s[3]); s[3] = fmaf(w0.w, s[3], a);
            a = b2f((u16)kv[4]) * vj; acc += b2f((u16)rv[4]) * fmaf(uu[4], a, s[4]); s[4] = fmaf(w1.x, s[4], a);
            a = b2f((u16)kv[5]) * vj; acc += b2f((u16)rv[5]) * fmaf(uu[5], a, s[5]); s[5] = fmaf(w1.y, s[5], a);
            a = b2f((u16)kv[6]) * vj; acc += b2f((u16)rv[6]) * fmaf(uu[6], a, s[6]); s[6] = fmaf(w1.z, s[6], a);
            a = b2f((u16)kv[7]) * vj; acc += b2f((u16)rv[7]) * fmaf(uu[7], a, s[7]); s[7] = fmaf(w1.w, s[7], a);
            accs[tt] = acc;
        }
        // reduction over ig (lane bits 0..2): xor1,xor2 on VALU (DPP), xor4 on LDS
#pragma unroll
        for (int tt = 0; tt < CT; tt++) accs[tt] += dpp_mov<0xB1>(accs[tt]);  // quad_perm(1,0,3,2)
#pragma unroll
        for (int tt = 0; tt < CT; tt++) accs[tt] += dpp_mov<0x4E>(accs[tt]);  // quad_perm(2,3,0,1)
#pragma unroll
        for (int tt = 0; tt < CT; tt++) accs[tt] = accs[tt] + swz_xor4(accs[tt]);
        if (ig == 0) {
            size_t offt = off0 + (size_t)c * CT * E + j;
#pragma unroll
            for (int tt = 0; tt < CT; tt++) out[offt + (size_t)tt * E] = accs[tt];
        }
        __syncthreads();
        cur ^= 1;
    }
}

// ---------------- 256x128 MFMA GEMM, 8-phase-style pipeline (K=2048) --------
// C[4096,2048] = ep( A[4096,2048](bf16) * Bw[2048,2048](bf16)^T )
// 512 thr, 8 waves as 4M x 2N (per-wave 64x64 -> best LDS reuse at BN=128).
// Triple-buffered LDS (144 KB): staging runs 2 K-tiles ahead; per K-tile the
// end wait is vmcnt(6) (this tile's 6 issues stay in flight) - never drains.
// 4 phases per K-tile: {ds_read cluster || 2 gl_lds16 -> s_barrier ->
// lgkmcnt(0) -> setprio(1) 8xMFMA setprio(0) -> s_barrier}.
// XOR chunk swizzle: store side pre-swizzles the GLOBAL source (LDS linear),
// read side applies pos = chunk ^ (row&7); uniform 8 accesses/bank.
// Grid 256 (16m x 16n) = 1 block/CU, XCD-bijective swizzle.
template <int EP>
__global__ __launch_bounds__(512, 2) void k_gemm256(const u16* __restrict__ A,
                                                    const u16* __restrict__ Bw,
                                                    void* __restrict__ C,
                                                    const float* __restrict__ emat1,
                                                    const float* __restrict__ emat2) {
    __shared__ u16 As[3][256 * 64];
    __shared__ u16 Bs[3][128 * 64];
    const int tid = threadIdx.x;
    const int bid = blockIdx.x;                 // 0..255
    const int sw = (bid & 7) * 32 + (bid >> 3); // bijective: 256 % 8 == 0
    const int m0 = (sw >> 4) << 8;              // 16 m-tiles of 256
    const int n0 = (sw & 15) << 7;              // 16 n-tiles of 128
    const int srow = tid >> 3;                  // 0..63
    const int schunk = (tid & 7) ^ (srow & 7);  // inverse-swizzled source chunk
    const u16* gA = A + (size_t)(m0 + srow) * E + schunk * 8;
    const u16* gB = Bw + (size_t)(n0 + srow) * E + schunk * 8;

    const int wv = tid >> 6, lane = tid & 63;
    const int wm = wv >> 1, wn = wv & 1;        // 4M x 2N wave grid
    const int lr = lane & 15, lq = lane >> 4;
    const int c0 = ((lq ^ (lr & 7)) << 3);      // kk=0 swizzled chunk (elems)
    const int c1 = (((4 + lq) ^ (lr & 7)) << 3);// kk=1
    const int arow = wm * 64 + lr;              // A row base (+mt*16)
    const int brow = wn * 64 + lr;              // B row base (+nt*16)

    f32x4 acc[4][4];
#pragma unroll
    for (int mt = 0; mt < 4; mt++)
#pragma unroll
        for (int nt = 0; nt < 4; nt++) acc[mt][nt] = {0.f, 0.f, 0.f, 0.f};

    const int NT = E / 64;                      // 32 K-tiles

    // full-tile stage (prologue only): 6 gl_lds16
    auto stage_full = [&](int kt, int buf) {
        const u16* a = gA + kt * 64;
        const u16* b = gB + kt * 64;
        u16* la = &As[buf][0] + tid * 8;
        u16* lb = &Bs[buf][0] + tid * 8;
        gl_lds16(a,                   la);
        gl_lds16(a + (size_t)64  * E, la + 64 * 64);
        gl_lds16(a + (size_t)128 * E, la + 128 * 64);
        gl_lds16(a + (size_t)192 * E, la + 192 * 64);
        gl_lds16(b,                   lb);
        gl_lds16(b + (size_t)64  * E, lb + 64 * 64);
    };

    stage_full(0, 0);
    stage_full(1, 1);
    asm volatile("s_waitcnt vmcnt(6)" ::: "memory");   // tile0 resident
    __builtin_amdgcn_s_barrier();

    for (int kt = 0; kt < NT; kt++) {
        const int rb = kt % 3;
        const int sb = (kt + 2) % 3;
        const bool st = (kt + 2) < NT;
        const u16* as = &As[rb][0];
        const u16* bs = &Bs[rb][0];
        const u16* ga = gA + (kt + 2) * 64;
        const u16* gb = gB + (kt + 2) * 64;
        u16* la = &As[sb][0] + tid * 8;
        u16* lb = &Bs[sb][0] + tid * 8;
        bf16x8 a0, a1, b0[4], b1[4];

        // ---- phase 0: A rows 0,16 @kk0 + all B @kk0 ; stage A blocks 0,64
        a0 = *reinterpret_cast<const bf16x8*>(as + (arow +  0) * 64 + c0);
        a1 = *reinterpret_cast<const bf16x8*>(as + (arow + 16) * 64 + c0);
#pragma unroll
        for (int nt = 0; nt < 4; nt++)
            b0[nt] = *reinterpret_cast<const bf16x8*>(bs + (brow + nt * 16) * 64 + c0);
        if (st) { gl_lds16(ga, la); gl_lds16(ga + (size_t)64 * E, la + 64 * 64); }
        __builtin_amdgcn_s_barrier();
        asm volatile("s_waitcnt lgkmcnt(0)" ::: "memory");
        __builtin_amdgcn_s_setprio(1);
#pragma unroll
        for (int nt = 0; nt < 4; nt++) {
            acc[0][nt] = __builtin_amdgcn_mfma_f32_16x16x32_bf16(a0, b0[nt], acc[0][nt], 0, 0, 0);
            acc[1][nt] = __builtin_amdgcn_mfma_f32_16x16x32_bf16(a1, b0[nt], acc[1][nt], 0, 0, 0);
        }
        __builtin_amdgcn_s_setprio(0);
        __builtin_amdgcn_s_barrier();

        // ---- phase 1: A rows 0,16 @kk1 + all B @kk1 ; stage A blocks 128,192
        a0 = *reinterpret_cast<const bf16x8*>(as + (arow +  0) * 64 + c1);
        a1 = *reinterpret_cast<const bf16x8*>(as + (arow + 16) * 64 + c1);
#pragma unroll
        for (int nt = 0; nt < 4; nt++)
            b1[nt] = *reinterpret_cast<const bf16x8*>(bs + (brow + nt * 16) * 64 + c1);
        if (st) { gl_lds16(ga + (size_t)128 * E, la + 128 * 64); gl_lds16(ga + (size_t)192 * E, la + 192 * 64); }
        __builtin_amdgcn_s_barrier();
        asm volatile("s_waitcnt lgkmcnt(0)" ::: "memory");
        __builtin_amdgcn_s_setprio(1);
#pragma unroll
        for (int nt = 0; nt < 4; nt++) {
            acc[0][nt] = __builtin_amdgcn_mfma_f32_16x16x32_bf16(a0, b1[nt], acc[0][nt], 0, 0, 0);
            acc[1][nt] = __builtin_amdgcn_mfma_f32_16x16x32_bf16(a1, b1[nt], acc[1][nt], 0, 0, 0);
        }
        __builtin_amdgcn_s_setprio(0);
        __builtin_amdgcn_s_barrier();

        // ---- phase 2: A rows 32,48 @kk0 (B kk0 in regs) ; stage B blocks 0,64
        a0 = *reinterpret_cast<const bf16x8*>(as + (arow + 32) * 64 + c0);
        a1 = *reinterpret_cast<const bf16x8*>(as + (arow + 48) * 64 + c0);
        if (st) { gl_lds16(gb, lb); gl_lds16(gb + (size_t)64 * E, lb + 64 * 64); }
        __builtin_amdgcn_s_barrier();
        asm volatile("s_waitcnt lgkmcnt(0)" ::: "memory");
        __builtin_amdgcn_s_setprio(1);
#pragma unroll
        for (int nt = 0; nt < 4; nt++) {
            acc[2][nt] = __builtin_amdgcn_mfma_f32_16x16x32_bf16(a0, b0[nt], acc[2][nt], 0, 0, 0);
            acc[3][nt] = __builtin_amdgcn_mfma_f32_16x16x32_bf16(a1, b0[nt], acc[3][nt], 0, 0, 0);
        }
        __builtin_amdgcn_s_setprio(0);
        __builtin_amdgcn_s_barrier();

        // ---- phase 3: A rows 32,48 @kk1 (B kk1 in regs) ; end-of-tile vmcnt
        a0 = *reinterpret_cast<const bf16x8*>(as + (arow + 32) * 64 + c1);
        a1 = *reinterpret_cast<const bf16x8*>(as + (arow + 48) * 64 + c1);
        if (st) asm volatile("s_waitcnt vmcnt(6)" ::: "memory");   // next tile resident, 6 in flight
        else    asm volatile("s_waitcnt vmcnt(0)" ::: "memory");
        __builtin_amdgcn_s_barrier();
        asm volatile("s_waitcnt lgkmcnt(0)" ::: "memory");
        __builtin_amdgcn_s_setprio(1);
#pragma unroll
        for (int nt = 0; nt < 4; nt++) {
            acc[2][nt] = __builtin_amdgcn_mfma_f32_16x16x32_bf16(a0, b1[nt], acc[2][nt], 0, 0, 0);
            acc[3][nt] = __builtin_amdgcn_mfma_f32_16x16x32_bf16(a1, b1[nt], acc[3][nt], 0, 0, 0);
        }
        __builtin_amdgcn_s_setprio(0);
        __builtin_amdgcn_s_barrier();
    }

    const int gmb = m0 + wm * 64 + (lq << 2);
    const int gnb = n0 + wn * 64 + lr;
#pragma unroll
    for (int mt = 0; mt < 4; mt++) {
#pragma unroll
        for (int nt = 0; nt < 4; nt++) {
            int gn = gnb + nt * 16;
#pragma unroll
            for (int i = 0; i < 4; i++) {
                int gm = gmb + mt * 16 + i;
                size_t idx = (size_t)gm * E + gn;
                float v = acc[mt][nt][i];
                if constexpr (EP == 5) ((float*)C)[idx] = emat1[idx] + v;
                else if constexpr (EP == 6) ((float*)C)[idx] = 1.f / (1.f + expf(-v));
                else if constexpr (EP == 7) { float t = fmaxf(v, 0.f); ((u16*)C)[idx] = f2b(t * t); }
                else if constexpr (EP == 8) ((float*)C)[idx] = emat1[idx] + emat2[idx] * v;
                else if constexpr (EP == 9) ((u16*)C)[idx] = f2b(v);
                else if constexpr (EP == 10) { float sg = 1.f / (1.f + expf(-v)); ((u16*)C)[idx] = f2b(v * sg); }
            }
        }
    }
}

// ---------------- 128x128 MFMA GEMM (m97 structure) — small-K EPs only -------
// EP: 2 xm(bf16) 3 decay(f32)
template <int EP>
__global__ __launch_bounds__(256) void k_gemm128(const u16* __restrict__ A, int lda,
                                                 const u16* __restrict__ Bw,
                                                 void* __restrict__ C, int K,
                                                 const float* __restrict__ evec,
                                                 const float* __restrict__ emat1,
                                                 const float* __restrict__ emat2) {
    __shared__ u16 As[128 * 32];
    __shared__ u16 Bs[128 * 32];
    const int tid = threadIdx.x;
    const int m0 = blockIdx.y << 7, n0 = blockIdx.x << 7;
    const int srow = tid >> 2;                                  // 0..63
    const int scol = (((tid & 3) ^ ((srow >> 1) & 3)) << 3);    // swizzled global chunk
    const int wv = tid >> 6, lane = tid & 63;
    const int wy = (wv >> 1) << 6, wx = (wv & 1) << 6;
    const int lr = lane & 15, lq = lane >> 4;
    const int cofs = ((lq ^ ((lr >> 1) & 3)) << 3);             // swizzled LDS chunk
    f32x4 acc[4][4];
#pragma unroll
    for (int a = 0; a < 4; a++)
#pragma unroll
        for (int bq = 0; bq < 4; bq++) acc[a][bq] = {0.f, 0.f, 0.f, 0.f};
    const u16* gA = A + (size_t)(m0 + srow) * lda + scol;
    const u16* gB = Bw + (size_t)(n0 + srow) * K + scol;
    u16* lA = As + srow * 32 + ((tid & 3) << 3);
    u16* lB = Bs + srow * 32 + ((tid & 3) << 3);
    for (int k0 = 0; k0 < K; k0 += 32) {
        gl_lds16(gA + k0, lA);
        gl_lds16(gA + (size_t)64 * lda + k0, lA + 64 * 32);
        gl_lds16(gB + k0, lB);
        gl_lds16(gB + (size_t)64 * K + k0, lB + 64 * 32);
        __syncthreads();     // drains vmcnt (compiler) -> LDS tiles ready
        bf16x8 af[4], bfr[4];
#pragma unroll
        for (int mt = 0; mt < 4; mt++)
            af[mt] = *reinterpret_cast<const bf16x8*>(As + (wy + mt * 16 + lr) * 32 + cofs);
#pragma unroll
        for (int nt = 0; nt < 4; nt++)
            bfr[nt] = *reinterpret_cast<const bf16x8*>(Bs + (wx + nt * 16 + lr) * 32 + cofs);
#pragma unroll
        for (int mt = 0; mt < 4; mt++)
#pragma unroll
            for (int nt = 0; nt < 4; nt++)
                acc[mt][nt] = __builtin_amdgcn_mfma_f32_16x16x32_bf16(af[mt], bfr[nt], acc[mt][nt], 0, 0, 0);
        __syncthreads();     // protect LDS before next iteration's staging
    }
    const int gmb = m0 + wy + (lq << 2);
    const int gnb = n0 + wx + lr;
#pragma unroll
    for (int mt = 0; mt < 4; mt++) {
#pragma unroll
        for (int nt = 0; nt < 4; nt++) {
            int gn = gnb + nt * 16;
#pragma unroll
            for (int i = 0; i < 4; i++) {
                int gm = gmb + mt * 16 + i;
                size_t idx = (size_t)gm * E + gn;
                float v = acc[mt][nt][i];
                if constexpr (EP == 2) {
                    int l = gm & (LL - 1), bb = gm >> 10;
                    float cur = emat1[idx];
                    float prev = (l > 0) ? emat1[idx - E]
                                         : emat2[(size_t)bb * 66 * E + E + gn];
                    ((u16*)C)[idx] = f2b(cur + (prev - cur) * (evec[gn] + v));
                }
                else if constexpr (EP == 3) ((float*)C)[idx] = expf(-expf(evec[gn] + v));
            }
        }
    }
}

// ---------------- 64-tile GEMM (odd N: 160 / 64), EP1 = tanh bf16 -----------
#define BK  32
#define LDP 40

template <int EP>
__global__ __launch_bounds__(256) void k_gemm(const u16* __restrict__ A, int lda,
                                              const u16* __restrict__ Bw,
                                              void* __restrict__ C,
                                              int M, int N, int K) {
    __shared__ u16 As[64 * LDP];
    __shared__ u16 Bs[64 * LDP];
    const int tid = threadIdx.x;
    const int m0 = blockIdx.y << 6, n0 = blockIdx.x << 6;
    const int srow = tid >> 2, skc = (tid & 3) << 3;
    const int lane = tid & 63, wv = tid >> 6;
    const int wr = (wv >> 1) << 5, wc = (wv & 1) << 5;
    const int lr = lane & 15, lq = lane >> 4;
    f32x4 acc[2][2];
#pragma unroll
    for (int a = 0; a < 2; a++)
#pragma unroll
        for (int bq = 0; bq < 2; bq++) acc[a][bq] = {0.f, 0.f, 0.f, 0.f};
    const u16* aptr = A + (size_t)(m0 + srow) * lda + skc;
    const u16* bptr = Bw + (size_t)(n0 + srow) * K + skc;
    const bool bvalid = (n0 + srow) < N;
    for (int k0 = 0; k0 < K; k0 += BK) {
        float4 av = *reinterpret_cast<const float4*>(aptr + k0);
        float4 bv = bvalid ? *reinterpret_cast<const float4*>(bptr + k0)
                           : make_float4(0.f, 0.f, 0.f, 0.f);
        __syncthreads();
        *reinterpret_cast<float4*>(As + srow * LDP + skc) = av;
        *reinterpret_cast<float4*>(Bs + srow * LDP + skc) = bv;
        __syncthreads();
        bf16x8 a0 = *reinterpret_cast<const bf16x8*>(As + (wr + lr) * LDP + lq * 8);
        bf16x8 a1 = *reinterpret_cast<const bf16x8*>(As + (wr + 16 + lr) * LDP + lq * 8);
        bf16x8 b0 = *reinterpret_cast<const bf16x8*>(Bs + (wc + lr) * LDP + lq * 8);
        bf16x8 b1 = *reinterpret_cast<const bf16x8*>(Bs + (wc + 16 + lr) * LDP + lq * 8);
        acc[0][0] = __builtin_amdgcn_mfma_f32_16x16x32_bf16(a0, b0, acc[0][0], 0, 0, 0);
        acc[0][1] = __builtin_amdgcn_mfma_f32_16x16x32_bf16(a0, b1, acc[0][1], 0, 0, 0);
        acc[1][0] = __builtin_amdgcn_mfma_f32_16x16x32_bf16(a1, b0, acc[1][0], 0, 0, 0);
        acc[1][1] = __builtin_amdgcn_mfma_f32_16x16x32_bf16(a1, b1, acc[1][1], 0, 0, 0);
    }
    const int gmb = m0 + wr + lq * 4;
    const int gnb = n0 + wc + lr;
#pragma unroll
    for (int mi = 0; mi < 2; mi++) {
#pragma unroll
        for (int ni = 0; ni < 2; ni++) {
            int gn = gnb + ni * 16;
            if (gn >= N) continue;
#pragma unroll
            for (int i = 0; i < 4; i++) {
                int gm = gmb + mi * 16 + i;
                size_t idx = (size_t)gm * N + gn;
                float v = acc[mi][ni][i];
                if constexpr (EP == 1) ((u16*)C)[idx] = f2b(tanhf(v));
            }
        }
    }
}

// ---------------- launch ----------------

extern "C" void kernel_launch(void* const* d_in, const int* in_sizes, int n_in,
                              void* d_out, int out_size, void* d_ws, size_t ws_size,
                              hipStream_t stream) {
    const float* x          = (const float*)d_in[0];
    const float* state      = (const float*)d_in[1];
    const float* ln1_w      = (const float*)d_in[2];
    const float* ln1_b      = (const float*)d_in[3];
    const float* ln2_w      = (const float*)d_in[4];
    const float* ln2_b      = (const float*)d_in[5];
    const float* maa_x      = (const float*)d_in[6];
    const float* maa_w1     = (const float*)d_in[7];
    const float* maa_w2     = (const float*)d_in[8];
    const float* maa_stack  = (const float*)d_in[9];
    const float* time_decay = (const float*)d_in[10];
    const float* td_w1      = (const float*)d_in[11];
    const float* td_w2      = (const float*)d_in[12];
    const float* u          = (const float*)d_in[13];
    const float* Wr         = (const float*)d_in[14];
    const float* Wk         = (const float*)d_in[15];
    const float* Wv         = (const float*)d_in[16];
    const float* Wg         = (const float*)d_in[17];
    const float* Wo         = (const float*)d_in[18];
    const float* gn_w       = (const float*)d_in[19];
    const float* gn_b       = (const float*)d_in[20];
    const float* ffn_k      = (const float*)d_in[21];
    const float* ffn_r      = (const float*)d_in[22];
    const float* Wfk        = (const float*)d_in[23];
    const float* Wfr        = (const float*)d_in[24];
    const float* Wfv        = (const float*)d_in[25];

    char* ws = (char*)d_ws;
    float* R0 = (float*)(ws);                        // xa -> wkv -> x1   (32 MiB f32)
    float* R1 = (float*)(ws + 33554432);             // Wdecay -> xc -> rr (32 MiB f32)
    u16*   R2 = (u16*)(ws + 67108864);               // mk/xm slot -> xk2 (16 MiB bf16)
    u16*   R3 = (u16*)(ws + 83886080);               // Rb -> xr2
    u16*   R4 = (u16*)(ws + 100663296);              // Kb -> kk
    u16*   R5 = (u16*)(ws + 117440512);              // Vb
    u16*   R6 = (u16*)(ws + 134217728);              // g -> ogg
    u16*   WB = (u16*)(ws + 150994944);              // weight bf16 slot (8 MiB)
    u16*   Hx = (u16*)(ws + 159383552);              // tanh(mk@w1)  NBL x 160
    u16*   Ht = (u16*)(ws + 160694272);              // tanh(xw@td1) NBL x 64
    u16*  WT1 = (u16*)(ws + 161218560);              // maa_w1^T  160 x 2048
    u16*  WT2 = (u16*)(ws + 161873920);              // maa_w2^T  5 x (2048 x 32)
    u16*  WT3 = (u16*)(ws + 162529280);              // td_w1^T   64 x 2048
    u16*  WT4 = (u16*)(ws + 162791424);              // td_w2^T   2048 x 64

    dim3 blk(256);
    dim3 blk512(512);
    dim3 g256(256);             // (4096/256) x (2048/128) = 256 tiles
    dim3 g128(16, 32);          // N=2048/128, M=4096/128 (small-K EPs)
    dim3 g160(3, 64), g64(1, 64);
    const int ncv = (E * E / 4) / 256;
    const int nel = NBLE / 1024;

    // small-weight transposes (to (N,K) bf16)
    k_transpose<<<(E * 160 + 255) / 256, blk, 0, stream>>>(maa_w1, WT1, E, 160);
    for (int f = 0; f < 5; f++)
        k_transpose<<<(32 * E + 255) / 256, blk, 0, stream>>>(maa_w2 + f * 32 * E, WT2 + f * E * 32, 32, E);
    k_transpose<<<(E * 64 + 255) / 256, blk, 0, stream>>>(td_w1, WT3, E, 64);
    k_transpose<<<(64 * E + 255) / 256, blk, 0, stream>>>(td_w2, WT4, 64, E);

    // time-mix front end
    k_ln<<<NBL, blk, 0, stream>>>(x, ln1_w, ln1_b, R0);                    // xa
    k_mk<<<nel, blk, 0, stream>>>(R0, state, maa_x, R2);                   // mk bf16
    k_gemm<1><<<g160, blk, 0, stream>>>(R2, E, WT1, Hx, NBL, 160, E);

    // decay chain (f=1: w)
    k_gemm128<2><<<g128, blk, 0, stream>>>(Hx + 1 * 32, 160, WT2 + 1 * E * 32, R2, 32,
                                           maa_stack + 1 * E, R0, state);
    k_gemm<1><<<g64, blk, 0, stream>>>(R2, E, WT3, Ht, NBL, 64, E);
    k_gemm128<3><<<g128, blk, 0, stream>>>(Ht, 64, WT4, R1, 64, time_decay, nullptr, nullptr);

    // k projection (f=0)
    k_gemm128<2><<<g128, blk, 0, stream>>>(Hx + 0 * 32, 160, WT2 + 0 * E * 32, R2, 32,
                                           maa_stack + 0 * E, R0, state);
    k_convert<<<ncv, blk, 0, stream>>>(Wk, WB, E * E);
    k_gemm256<9><<<g256, blk512, 0, stream>>>(R2, WB, R4, nullptr, nullptr);

    // v projection (f=2)
    k_gemm128<2><<<g128, blk, 0, stream>>>(Hx + 2 * 32, 160, WT2 + 2 * E * 32, R2, 32,
                                           maa_stack + 2 * E, R0, state);
    k_convert<<<ncv, blk, 0, stream>>>(Wv, WB, E * E);
    k_gemm256<9><<<g256, blk512, 0, stream>>>(R2, WB, R5, nullptr, nullptr);

    // g projection (f=4)
    k_gemm128<2><<<g128, blk, 0, stream>>>(Hx + 4 * 32, 160, WT2 + 4 * E * 32, R2, 32,
                                           maa_stack + 4 * E, R0, state);
    k_convert<<<ncv, blk, 0, stream>>>(Wg, WB, E * E);
    k_gemm256<10><<<g256, blk512, 0, stream>>>(R2, WB, R6, nullptr, nullptr);

    // r projection (f=3) — last use of xa (R0)
    k_gemm128<2><<<g128, blk, 0, stream>>>(Hx + 3 * 32, 160, WT2 + 3 * E * 32, R2, 32,
                                           maa_stack + 3 * E, R0, state);
    k_convert<<<ncv, blk, 0, stream>>>(Wr, WB, E * E);
    k_gemm256<9><<<g256, blk512, 0, stream>>>(R2, WB, R3, nullptr, nullptr);

    // sequential WKV scan -> R0 (wkv f32), then groupnorm * g -> ogg (R6 in place)
    k_scan<<<512, dim3(128), 0, stream>>>(R3, R4, R5, R1, state, u, R0);
    k_gnorm<<<NBL * HHH / 4, blk, 0, stream>>>(R0, R6, gn_w, gn_b, R6);

    // output projection + residual -> x1 (R0; wkv dead)
    k_convert<<<ncv, blk, 0, stream>>>(Wo, WB, E * E);
    k_gemm256<5><<<g256, blk512, 0, stream>>>(R6, WB, R0, x, nullptr);

    // channel mix
    k_ln<<<NBL, blk, 0, stream>>>(R0, ln2_w, ln2_b, R1);                   // xc
    k_mix2<<<nel, blk, 0, stream>>>(R1, state, ffn_k, ffn_r, R2, R3);      // xk2, xr2
    k_convert<<<ncv, blk, 0, stream>>>(Wfk, WB, E * E);
    k_gemm256<7><<<g256, blk512, 0, stream>>>(R2, WB, R4, nullptr, nullptr);
    k_convert<<<ncv, blk, 0, stream>>>(Wfr, WB, E * E);
    k_gemm256<6><<<g256, blk512, 0, stream>>>(R3, WB, R1, nullptr, nullptr);
    k_convert<<<ncv, blk, 0, stream>>>(Wfv, WB, E * E);
    k_gemm256<8><<<g256, blk512, 0, stream>>>(R4, WB, (float*)d_out, R0, R1);
}

// Round 6
// 962.727 us; speedup vs baseline: 1.2112x; 1.2112x over previous
//
#include <hip/hip_runtime.h>

// RWKV-6 style block on MI355X (gfx950).
// E=2048, H=32, S=64, L=1024, B=4.
// Round 11: (a) k_gemm256: SAFE 2-phase pipeline (round-8 ordering invariants:
//           stage -> [vmcnt] -> barrier -> lgkm0 -> MFMA -> barrier; counted
//           vmcnt(6) once per K-tile).  4 barriers/tile vs round-8's 8,
//           16 MFMA + 8 ds_read + 3 gl_lds per phase (m201 cadence).
//           Round-10's single-barrier form was racy (per-wave vmcnt is not
//           collective residency) - abandoned.
//           (b) k_scan: round-3 geometry, ig remapped to lane bits {0,1,4,5}
//           so reduction stages xor1/xor2 run as DPP quad_perm VALU adds
//           (off the LDS pipe); only xor16/xor32 remain as shuffles.

#define E     2048
#define LL    1024
#define HHH   32
#define SSS   64
#define NBL   4096      // B*L
#define NBLE  8388608   // B*L*E

typedef short bf16x8 __attribute__((ext_vector_type(8)));
typedef float f32x4  __attribute__((ext_vector_type(4)));
using u16 = unsigned short;

__device__ __forceinline__ u16 f2b(float f) {
    union { float f; unsigned int u; } c; c.f = f;
    unsigned int u = c.u;
    unsigned int r = (u + 0x7fffu + ((u >> 16) & 1u)) >> 16;
    return (u16)r;
}
__device__ __forceinline__ float b2f(u16 b) {
    union { unsigned int u; float f; } c; c.u = ((unsigned int)b) << 16; return c.f;
}

__device__ __forceinline__ float wave_sum(float v) {
#pragma unroll
    for (int m = 32; m >= 1; m >>= 1) v += __shfl_xor(v, m, 64);
    return v;
}

__device__ __forceinline__ void gl_lds16(const void* g, void* l) {
    __builtin_amdgcn_global_load_lds((const __attribute__((address_space(1))) unsigned int*)g,
                                     (__attribute__((address_space(3))) unsigned int*)l, 16, 0, 0);
}

// DPP cross-lane move within quads (VALU pipe, not LDS)
template <int CTRL>
__device__ __forceinline__ float dpp_mov(float v) {
    int s = __builtin_bit_cast(int, v);
    int r = __builtin_amdgcn_update_dpp(s, s, CTRL, 0xF, 0xF, false);
    return __builtin_bit_cast(float, r);
}

// ---------------- elementwise / prep kernels ----------------

__global__ __launch_bounds__(256) void k_convert(const float* __restrict__ in,
                                                 u16* __restrict__ out, int n) {
    int i = (blockIdx.x * 256 + threadIdx.x) * 4;
    if (i >= n) return;
    float4 v = *reinterpret_cast<const float4*>(in + i);
    ushort4 o = make_ushort4(f2b(v.x), f2b(v.y), f2b(v.z), f2b(v.w));
    *reinterpret_cast<ushort4*>(out + i) = o;
}

// in (R,C) fp32 -> out (C,R) bf16
__global__ __launch_bounds__(256) void k_transpose(const float* __restrict__ in,
                                                   u16* __restrict__ out, int R, int C) {
    int i = blockIdx.x * 256 + threadIdx.x;
    if (i >= R * C) return;
    int r = i / C, c = i - r * C;
    out[c * R + r] = f2b(in[i]);
}

__global__ __launch_bounds__(256) void k_ln(const float* __restrict__ x,
                                            const float* __restrict__ w,
                                            const float* __restrict__ b,
                                            float* __restrict__ out) {
    int row = blockIdx.x, tid = threadIdx.x;
    const float* xr = x + (size_t)row * E + tid * 8;
    float4 v0 = *reinterpret_cast<const float4*>(xr);
    float4 v1 = *reinterpret_cast<const float4*>(xr + 4);
    float s = v0.x + v0.y + v0.z + v0.w + v1.x + v1.y + v1.z + v1.w;
    __shared__ float red[4];
    s = wave_sum(s);
    int wid = tid >> 6, lane = tid & 63;
    if (lane == 0) red[wid] = s;
    __syncthreads();
    float mean = (red[0] + red[1] + red[2] + red[3]) * (1.0f / E);
    __syncthreads();
    float q = 0.f;
    q += (v0.x - mean) * (v0.x - mean); q += (v0.y - mean) * (v0.y - mean);
    q += (v0.z - mean) * (v0.z - mean); q += (v0.w - mean) * (v0.w - mean);
    q += (v1.x - mean) * (v1.x - mean); q += (v1.y - mean) * (v1.y - mean);
    q += (v1.z - mean) * (v1.z - mean); q += (v1.w - mean) * (v1.w - mean);
    q = wave_sum(q);
    if (lane == 0) red[wid] = q;
    __syncthreads();
    float inv = rsqrtf((red[0] + red[1] + red[2] + red[3]) * (1.0f / E) + 1e-5f);
    int e = tid * 8;
    float4 w0 = *reinterpret_cast<const float4*>(w + e);
    float4 w1 = *reinterpret_cast<const float4*>(w + e + 4);
    float4 b0 = *reinterpret_cast<const float4*>(b + e);
    float4 b1 = *reinterpret_cast<const float4*>(b + e + 4);
    float4 o0, o1;
    o0.x = (v0.x - mean) * inv * w0.x + b0.x; o0.y = (v0.y - mean) * inv * w0.y + b0.y;
    o0.z = (v0.z - mean) * inv * w0.z + b0.z; o0.w = (v0.w - mean) * inv * w0.w + b0.w;
    o1.x = (v1.x - mean) * inv * w1.x + b1.x; o1.y = (v1.y - mean) * inv * w1.y + b1.y;
    o1.z = (v1.z - mean) * inv * w1.z + b1.z; o1.w = (v1.w - mean) * inv * w1.w + b1.w;
    float* op = out + (size_t)row * E + e;
    *reinterpret_cast<float4*>(op) = o0;
    *reinterpret_cast<float4*>(op + 4) = o1;
}

// mk = bf16(xa + sx*maa_x), sx recomputed inline (time-mix shift, state row 1)
__global__ __launch_bounds__(256) void k_mk(const float* __restrict__ xa,
                                            const float* __restrict__ state,
                                            const float* __restrict__ maa_x,
                                            u16* __restrict__ out) {
    int i = (blockIdx.x * 256 + threadIdx.x) * 4;
    if (i >= NBLE) return;
    int n = i >> 11, e = i & (E - 1);
    int l = n & (LL - 1), b = n >> 10;
    float4 cur = *reinterpret_cast<const float4*>(xa + i);
    float4 prev;
    if (l > 0) prev = *reinterpret_cast<const float4*>(xa + i - E);
    else       prev = *reinterpret_cast<const float4*>(state + (size_t)b * 66 * E + E + e);
    float4 m = *reinterpret_cast<const float4*>(maa_x + e);
    ushort4 o = make_ushort4(f2b(cur.x + (prev.x - cur.x) * m.x),
                             f2b(cur.y + (prev.y - cur.y) * m.y),
                             f2b(cur.z + (prev.z - cur.z) * m.z),
                             f2b(cur.w + (prev.w - cur.w) * m.w));
    *reinterpret_cast<ushort4*>(out + i) = o;
}

// channel-mix token shift (state row 0) + two mixes -> bf16
__global__ __launch_bounds__(256) void k_mix2(const float* __restrict__ xc,
                                              const float* __restrict__ state,
                                              const float* __restrict__ mk,
                                              const float* __restrict__ mr,
                                              u16* __restrict__ xk2,
                                              u16* __restrict__ xr2) {
    int i = (blockIdx.x * 256 + threadIdx.x) * 4;
    if (i >= NBLE) return;
    int n = i >> 11, e = i & (E - 1);
    int l = n & (LL - 1), b = n >> 10;
    float4 cur = *reinterpret_cast<const float4*>(xc + i);
    float4 prev;
    if (l > 0) prev = *reinterpret_cast<const float4*>(xc + i - E);
    else       prev = *reinterpret_cast<const float4*>(state + (size_t)b * 66 * E + e);
    float4 sx = make_float4(prev.x - cur.x, prev.y - cur.y, prev.z - cur.z, prev.w - cur.w);
    float4 k4 = *reinterpret_cast<const float4*>(mk + e);
    float4 r4 = *reinterpret_cast<const float4*>(mr + e);
    ushort4 ok = make_ushort4(f2b(cur.x + sx.x * k4.x), f2b(cur.y + sx.y * k4.y),
                              f2b(cur.z + sx.z * k4.z), f2b(cur.w + sx.w * k4.w));
    ushort4 orr = make_ushort4(f2b(cur.x + sx.x * r4.x), f2b(cur.y + sx.y * r4.y),
                               f2b(cur.z + sx.z * r4.z), f2b(cur.w + sx.w * r4.w));
    *reinterpret_cast<ushort4*>(xk2 + i) = ok;
    *reinterpret_cast<ushort4*>(xr2 + i) = orr;
}

// per-head groupnorm over S=64, *gn_w+gn_b, *g (bf16, in-place ok) -> bf16
__global__ __launch_bounds__(256) void k_gnorm(const float* __restrict__ wkv,
                                               const u16* __restrict__ g,
                                               const float* __restrict__ gw,
                                               const float* __restrict__ gb,
                                               u16* __restrict__ ogg) {
    int gidx = blockIdx.x * 4 + (threadIdx.x >> 6);
    int lane = threadIdx.x & 63;
    int n = gidx >> 5, h = gidx & 31;
    size_t base = (size_t)n * E + h * SSS;
    float v = wkv[base + lane];
    float mean = wave_sum(v) * (1.0f / SSS);
    float d = v - mean;
    float var = wave_sum(d * d) * (1.0f / SSS);
    float norm = d * rsqrtf(var + 1e-5f);
    int e = h * SSS + lane;
    float res = norm * gw[e] + gb[e];
    float gv = b2f(g[base + lane]);
    ogg[base + lane] = f2b(res * gv);
}

// ---------------- WKV sequential scan (round-3 geometry + DPP reduction) ----
// grid = B*H*4 = 512 blocks of 256 (4 waves, 2 blocks/CU).  Block = (b,h,jq),
// (b,h) fastest in blockIdx.  Lane owns 4 state rows of one j-column.
// ig occupies lane bits {0,1,4,5}; jl bits {2,3}.  Reduction over ig:
// xor-bit0/bit1 via DPP quad_perm (VALU pipe), xor16/xor32 via batched shfl.
// 16-timestep chunks staged via global_load_lds, double buffered.
#define CT 16

__global__ __launch_bounds__(256) void k_scan(const u16* __restrict__ Rb,
                                              const u16* __restrict__ Kb,
                                              const u16* __restrict__ Vb,
                                              const float* __restrict__ W,
                                              const float* __restrict__ state,
                                              const float* __restrict__ u,
                                              float* __restrict__ out) {
    __shared__ u16   ldsR[2][CT * 64];
    __shared__ u16   ldsK[2][CT * 64];
    __shared__ float ldsW[2][CT * 64];
    __shared__ u16   ldsV[2][CT * 16];
    const int blk = blockIdx.x;
    const int bh = blk & 127;            // (b,h) fastest
    const int jq = blk >> 7;             // 0..3  (16 j-columns each)
    const int b = bh >> 5, h = bh & 31;
    const int tid = threadIdx.x;
    const int wvid = tid >> 6;           // 0..3
    const int lane = tid & 63;
    const int ig = (lane & 3) | (((lane >> 4) & 3) << 2);   // bits 0,1,4,5
    const int jl = (lane >> 2) & 3;                          // bits 2,3
    const int jv = wvid * 4 + jl;        // 0..15
    const int j  = jq * 16 + jv;
    const int i0 = ig * 4;
    float s[4], uu[4];
    const float* s0 = state + (size_t)b * 66 * E + 2 * E + h * (SSS * SSS);
#pragma unroll
    for (int ii = 0; ii < 4; ii++) {
        s[ii] = s0[(i0 + ii) * SSS + j];
        uu[ii] = u[h * SSS + i0 + ii];
    }
    const size_t off0 = (size_t)b * LL * E + h * SSS;

    auto stage = [&](int c, int bufsel) {
        size_t base = off0 + (size_t)c * CT * E;
        if (wvid == 0) {
            const u16* g0 = Rb + base + (size_t)(lane >> 3) * E + ((lane & 7) << 3);
            gl_lds16(g0,         &ldsR[bufsel][lane * 8]);
            gl_lds16(g0 + 8 * E, &ldsR[bufsel][512 + lane * 8]);
            if (lane < 32) {
                const u16* gv = Vb + base + (size_t)(lane >> 1) * E + jq * 16 + ((lane & 1) << 3);
                gl_lds16(gv, &ldsV[bufsel][lane * 8]);
            }
        } else if (wvid == 1) {
            const u16* g0 = Kb + base + (size_t)(lane >> 3) * E + ((lane & 7) << 3);
            gl_lds16(g0,         &ldsK[bufsel][lane * 8]);
            gl_lds16(g0 + 8 * E, &ldsK[bufsel][512 + lane * 8]);
        } else if (wvid == 2) {
            const float* g0 = W + base + (size_t)(lane >> 4) * E + ((lane & 15) << 2);
            gl_lds16(g0,         &ldsW[bufsel][lane * 4]);
            gl_lds16(g0 + 4 * E, &ldsW[bufsel][256 + lane * 4]);
        } else {
            const float* g0 = W + base + (size_t)(8 + (lane >> 4)) * E + ((lane & 15) << 2);
            gl_lds16(g0,         &ldsW[bufsel][512 + lane * 4]);
            gl_lds16(g0 + 4 * E, &ldsW[bufsel][768 + lane * 4]);
        }
    };

    stage(0, 0);
    __syncthreads();
    int cur = 0;
    for (int c = 0; c < LL / CT; c++) {
        if (c + 1 < LL / CT) stage(c + 1, cur ^ 1);
        float accs[CT];
#pragma unroll
        for (int tt = 0; tt < CT; tt++) {
            ushort4 rv = *reinterpret_cast<const ushort4*>(&ldsR[cur][tt * 64 + i0]);
            ushort4 kv = *reinterpret_cast<const ushort4*>(&ldsK[cur][tt * 64 + i0]);
            float4  wv = *reinterpret_cast<const float4*>(&ldsW[cur][tt * 64 + i0]);
            float vj = b2f(ldsV[cur][tt * 16 + jv]);
            float acc = 0.f, a;
            a = b2f(kv.x) * vj; acc += b2f(rv.x) * fmaf(uu[0], a, s[0]); s[0] = fmaf(wv.x, s[0], a);
            a = b2f(kv.y) * vj; acc += b2f(rv.y) * fmaf(uu[1], a, s[1]); s[1] = fmaf(wv.y, s[1], a);
            a = b2f(kv.z) * vj; acc += b2f(rv.z) * fmaf(uu[2], a, s[2]); s[2] = fmaf(wv.z, s[2], a);
            a = b2f(kv.w) * vj; acc += b2f(rv.w) * fmaf(uu[3], a, s[3]); s[3] = fmaf(wv.w, s[3], a);
            accs[tt] = acc;
        }
        // reduce over ig bits: 0 -> quad_perm(1,0,3,2), 1 -> quad_perm(2,3,0,1),
        // then xor16 / xor32 as batched shuffles (latency pipelines across tt).
#pragma unroll
        for (int tt = 0; tt < CT; tt++) accs[tt] += dpp_mov<0xB1>(accs[tt]);
#pragma unroll
        for (int tt = 0; tt < CT; tt++) accs[tt] += dpp_mov<0x4E>(accs[tt]);
#pragma unroll
        for (int tt = 0; tt < CT; tt++) accs[tt] += __shfl_xor(accs[tt], 16, 64);
#pragma unroll
        for (int tt = 0; tt < CT; tt++) accs[tt] += __shfl_xor(accs[tt], 32, 64);
        if (ig == 0) {
            size_t offt = off0 + (size_t)c * CT * E + j;
#pragma unroll
            for (int tt = 0; tt < CT; tt++) out[offt + (size_t)tt * E] = accs[tt];
        }
        __syncthreads();
        cur ^= 1;
    }
}

// ---------------- 256x128 MFMA GEMM, 2-phase pipeline (K=2048) --------------
// C[4096,2048] = ep( A[4096,2048](bf16) * Bw[2048,2048](bf16)^T )
// 512 thr, 8 waves as 4M x 2N (64x64/wave).  Triple-buffered LDS (144 KB),
// staging 2 K-tiles ahead.  2 phases per K-tile, each
// {8 ds_read_b128 ; 3 gl_lds16 -> s_barrier -> lgkm0 -> setprio + 16 MFMA ->
//  s_barrier}; counted vmcnt(6) before phase-1's first barrier (round-8-safe:
// barrier AFTER vmcnt makes residency collective).  4 barriers/K-tile.
// XOR chunk swizzle (pre-swizzled global source + swizzled ds_read).
// Grid 256 (16m x 16n) = 1 block/CU, XCD-bijective swizzle.
template <int EP>
__global__ __launch_bounds__(512, 2) void k_gemm256(const u16* __restrict__ A,
                                                    const u16* __restrict__ Bw,
                                                    void* __restrict__ C,
                                                    const float* __restrict__ emat1,
                                                    const float* __restrict__ emat2) {
    __shared__ u16 As[3][256 * 64];
    __shared__ u16 Bs[3][128 * 64];
    const int tid = threadIdx.x;
    const int bid = blockIdx.x;                 // 0..255
    const int sw = (bid & 7) * 32 + (bid >> 3); // bijective: 256 % 8 == 0
    const int m0 = (sw >> 4) << 8;              // 16 m-tiles of 256
    const int n0 = (sw & 15) << 7;              // 16 n-tiles of 128
    const int srow = tid >> 3;                  // 0..63
    const int schunk = (tid & 7) ^ (srow & 7);  // inverse-swizzled source chunk
    const u16* gA = A + (size_t)(m0 + srow) * E + schunk * 8;
    const u16* gB = Bw + (size_t)(n0 + srow) * E + schunk * 8;

    const int wv = tid >> 6, lane = tid & 63;
    const int wm = wv >> 1, wn = wv & 1;        // 4M x 2N wave grid
    const int lr = lane & 15, lq = lane >> 4;
    const int c0 = ((lq ^ (lr & 7)) << 3);      // kk=0 swizzled chunk (elems)
    const int c1 = (((4 + lq) ^ (lr & 7)) << 3);// kk=1
    const int arow = wm * 64 + lr;              // A row base (+mt*16)
    const int brow = wn * 64 + lr;              // B row base (+nt*16)

    f32x4 acc[4][4];
#pragma unroll
    for (int mt = 0; mt < 4; mt++)
#pragma unroll
        for (int nt = 0; nt < 4; nt++) acc[mt][nt] = {0.f, 0.f, 0.f, 0.f};

    const int NT = E / 64;                      // 32 K-tiles

    // full-tile stage (prologue only): 6 gl_lds16
    auto stage_full = [&](int kt, int buf) {
        const u16* a = gA + kt * 64;
        const u16* b = gB + kt * 64;
        u16* la = &As[buf][0] + tid * 8;
        u16* lb = &Bs[buf][0] + tid * 8;
        gl_lds16(a,                   la);
        gl_lds16(a + (size_t)64  * E, la + 64 * 64);
        gl_lds16(a + (size_t)128 * E, la + 128 * 64);
        gl_lds16(a + (size_t)192 * E, la + 192 * 64);
        gl_lds16(b,                   lb);
        gl_lds16(b + (size_t)64  * E, lb + 64 * 64);
    };

    stage_full(0, 0);
    stage_full(1, 1);
    asm volatile("s_waitcnt vmcnt(6)" ::: "memory");   // tile0 resident (own)
    __builtin_amdgcn_s_barrier();                      // collective residency

    for (int kt = 0; kt < NT; kt++) {
        const int rb = kt % 3;
        const int sb = (kt + 2) % 3;
        const bool st = (kt + 2) < NT;
        const u16* as = &As[rb][0];
        const u16* bs = &Bs[rb][0];
        const u16* ga = gA + (kt + 2) * 64;
        const u16* gb = gB + (kt + 2) * 64;
        u16* la = &As[sb][0] + tid * 8;
        u16* lb = &Bs[sb][0] + tid * 8;
        bf16x8 a0[4], a1[4], b0[4], b1[4];

        // ---- phase 0: kk0 fragments ; stage A blocks 0,64,128
        #pragma unroll
        for (int mt = 0; mt < 4; mt++)
            a0[mt] = *reinterpret_cast<const bf16x8*>(as + (arow + mt * 16) * 64 + c0);
        #pragma unroll
        for (int nt = 0; nt < 4; nt++)
            b0[nt] = *reinterpret_cast<const bf16x8*>(bs + (brow + nt * 16) * 64 + c0);
        if (st) {
            gl_lds16(ga,                   la);
            gl_lds16(ga + (size_t)64  * E, la + 64 * 64);
            gl_lds16(ga + (size_t)128 * E, la + 128 * 64);
        }
        __builtin_amdgcn_s_barrier();
        asm volatile("s_waitcnt lgkmcnt(0)" ::: "memory");
        __builtin_amdgcn_s_setprio(1);
        #pragma unroll
        for (int mt = 0; mt < 4; mt++)
            #pragma unroll
            for (int nt = 0; nt < 4; nt++)
                acc[mt][nt] = __builtin_amdgcn_mfma_f32_16x16x32_bf16(a0[mt], b0[nt], acc[mt][nt], 0, 0, 0);
        __builtin_amdgcn_s_setprio(0);
        __builtin_amdgcn_s_barrier();

        // ---- phase 1: kk1 fragments ; stage A block 192 + B blocks 0,64 ;
        //      counted vmcnt -> next tile collectively resident after barrier
        #pragma unroll
        for (int mt = 0; mt < 4; mt++)
            a1[mt] = *reinterpret_cast<const bf16x8*>(as + (arow + mt * 16) * 64 + c1);
        #pragma unroll
        for (int nt = 0; nt < 4; nt++)
            b1[nt] = *reinterpret_cast<const bf16x8*>(bs + (brow + nt * 16) * 64 + c1);
        if (st) {
            gl_lds16(ga + (size_t)192 * E, la + 192 * 64);
            gl_lds16(gb,                   lb);
            gl_lds16(gb + (size_t)64  * E, lb + 64 * 64);
            asm volatile("s_waitcnt vmcnt(6)" ::: "memory");  // kt+1 landed, kt+2 in flight
        } else {
            asm volatile("s_waitcnt vmcnt(0)" ::: "memory");
        }
        __builtin_amdgcn_s_barrier();
        asm volatile("s_waitcnt lgkmcnt(0)" ::: "memory");
        __builtin_amdgcn_s_setprio(1);
        #pragma unroll
        for (int mt = 0; mt < 4; mt++)
            #pragma unroll
            for (int nt = 0; nt < 4; nt++)
                acc[mt][nt] = __builtin_amdgcn_mfma_f32_16x16x32_bf16(a1[mt], b1[nt], acc[mt][nt], 0, 0, 0);
        __builtin_amdgcn_s_setprio(0);
        __builtin_amdgcn_s_barrier();
    }

    const int gmb = m0 + wm * 64 + (lq << 2);
    const int gnb = n0 + wn * 64 + lr;
#pragma unroll
    for (int mt = 0; mt < 4; mt++) {
#pragma unroll
        for (int nt = 0; nt < 4; nt++) {
            int gn = gnb + nt * 16;
#pragma unroll
            for (int i = 0; i < 4; i++) {
                int gm = gmb + mt * 16 + i;
                size_t idx = (size_t)gm * E + gn;
                float v = acc[mt][nt][i];
                if constexpr (EP == 5) ((float*)C)[idx] = emat1[idx] + v;
                else if constexpr (EP == 6) ((float*)C)[idx] = 1.f / (1.f + expf(-v));
                else if constexpr (EP == 7) { float t = fmaxf(v, 0.f); ((u16*)C)[idx] = f2b(t * t); }
                else if constexpr (EP == 8) ((float*)C)[idx] = emat1[idx] + emat2[idx] * v;
                else if constexpr (EP == 9) ((u16*)C)[idx] = f2b(v);
                else if constexpr (EP == 10) { float sg = 1.f / (1.f + expf(-v)); ((u16*)C)[idx] = f2b(v * sg); }
            }
        }
    }
}

// ---------------- 128x128 MFMA GEMM (m97 structure) — small-K EPs only -------
// EP: 2 xm(bf16) 3 decay(f32)
template <int EP>
__global__ __launch_bounds__(256) void k_gemm128(const u16* __restrict__ A, int lda,
                                                 const u16* __restrict__ Bw,
                                                 void* __restrict__ C, int K,
                                                 const float* __restrict__ evec,
                                                 const float* __restrict__ emat1,
                                                 const float* __restrict__ emat2) {
    __shared__ u16 As[128 * 32];
    __shared__ u16 Bs[128 * 32];
    const int tid = threadIdx.x;
    const int m0 = blockIdx.y << 7, n0 = blockIdx.x << 7;
    const int srow = tid >> 2;                                  // 0..63
    const int scol = (((tid & 3) ^ ((srow >> 1) & 3)) << 3);    // swizzled global chunk
    const int wv = tid >> 6, lane = tid & 63;
    const int wy = (wv >> 1) << 6, wx = (wv & 1) << 6;
    const int lr = lane & 15, lq = lane >> 4;
    const int cofs = ((lq ^ ((lr >> 1) & 3)) << 3);             // swizzled LDS chunk
    f32x4 acc[4][4];
#pragma unroll
    for (int a = 0; a < 4; a++)
#pragma unroll
        for (int bq = 0; bq < 4; bq++) acc[a][bq] = {0.f, 0.f, 0.f, 0.f};
    const u16* gA = A + (size_t)(m0 + srow) * lda + scol;
    const u16* gB = Bw + (size_t)(n0 + srow) * K + scol;
    u16* lA = As + srow * 32 + ((tid & 3) << 3);
    u16* lB = Bs + srow * 32 + ((tid & 3) << 3);
    for (int k0 = 0; k0 < K; k0 += 32) {
        gl_lds16(gA + k0, lA);
        gl_lds16(gA + (size_t)64 * lda + k0, lA + 64 * 32);
        gl_lds16(gB + k0, lB);
        gl_lds16(gB + (size_t)64 * K + k0, lB + 64 * 32);
        __syncthreads();     // drains vmcnt (compiler) -> LDS tiles ready
        bf16x8 af[4], bfr[4];
#pragma unroll
        for (int mt = 0; mt < 4; mt++)
            af[mt] = *reinterpret_cast<const bf16x8*>(As + (wy + mt * 16 + lr) * 32 + cofs);
#pragma unroll
        for (int nt = 0; nt < 4; nt++)
            bfr[nt] = *reinterpret_cast<const bf16x8*>(Bs + (wx + nt * 16 + lr) * 32 + cofs);
#pragma unroll
        for (int mt = 0; mt < 4; mt++)
#pragma unroll
            for (int nt = 0; nt < 4; nt++)
                acc[mt][nt] = __builtin_amdgcn_mfma_f32_16x16x32_bf16(af[mt], bfr[nt], acc[mt][nt], 0, 0, 0);
        __syncthreads();     // protect LDS before next iteration's staging
    }
    const int gmb = m0 + wy + (lq << 2);
    const int gnb = n0 + wx + lr;
#pragma unroll
    for (int mt = 0; mt < 4; mt++) {
#pragma unroll
        for (int nt = 0; nt < 4; nt++) {
            int gn = gnb + nt * 16;
#pragma unroll
            for (int i = 0; i < 4; i++) {
                int gm = gmb + mt * 16 + i;
                size_t idx = (size_t)gm * E + gn;
                float v = acc[mt][nt][i];
                if constexpr (EP == 2) {
                    int l = gm & (LL - 1), bb = gm >> 10;
                    float cur = emat1[idx];
                    float prev = (l > 0) ? emat1[idx - E]
                                         : emat2[(size_t)bb * 66 * E + E + gn];
                    ((u16*)C)[idx] = f2b(cur + (prev - cur) * (evec[gn] + v));
                }
                else if constexpr (EP == 3) ((float*)C)[idx] = expf(-expf(evec[gn] + v));
            }
        }
    }
}

// ---------------- 64-tile GEMM (odd N: 160 / 64), EP1 = tanh bf16 -----------
#define BK  32
#define LDP 40

template <int EP>
__global__ __launch_bounds__(256) void k_gemm(const u16* __restrict__ A, int lda,
                                              const u16* __restrict__ Bw,
                                              void* __restrict__ C,
                                              int M, int N, int K) {
    __shared__ u16 As[64 * LDP];
    __shared__ u16 Bs[64 * LDP];
    const int tid = threadIdx.x;
    const int m0 = blockIdx.y << 6, n0 = blockIdx.x << 6;
    const int srow = tid >> 2, skc = (tid & 3) << 3;
    const int lane = tid & 63, wv = tid >> 6;
    const int wr = (wv >> 1) << 5, wc = (wv & 1) << 5;
    const int lr = lane & 15, lq = lane >> 4;
    f32x4 acc[2][2];
#pragma unroll
    for (int a = 0; a < 2; a++)
#pragma unroll
        for (int bq = 0; bq < 2; bq++) acc[a][bq] = {0.f, 0.f, 0.f, 0.f};
    const u16* aptr = A + (size_t)(m0 + srow) * lda + skc;
    const u16* bptr = Bw + (size_t)(n0 + srow) * K + skc;
    const bool bvalid = (n0 + srow) < N;
    for (int k0 = 0; k0 < K; k0 += BK) {
        float4 av = *reinterpret_cast<const float4*>(aptr + k0);
        float4 bv = bvalid ? *reinterpret_cast<const float4*>(bptr + k0)
                           : make_float4(0.f, 0.f, 0.f, 0.f);
        __syncthreads();
        *reinterpret_cast<float4*>(As + srow * LDP + skc) = av;
        *reinterpret_cast<float4*>(Bs + srow * LDP + skc) = bv;
        __syncthreads();
        bf16x8 a0 = *reinterpret_cast<const bf16x8*>(As + (wr + lr) * LDP + lq * 8);
        bf16x8 a1 = *reinterpret_cast<const bf16x8*>(As + (wr + 16 + lr) * LDP + lq * 8);
        bf16x8 b0 = *reinterpret_cast<const bf16x8*>(Bs + (wc + lr) * LDP + lq * 8);
        bf16x8 b1 = *reinterpret_cast<const bf16x8*>(Bs + (wc + 16 + lr) * LDP + lq * 8);
        acc[0][0] = __builtin_amdgcn_mfma_f32_16x16x32_bf16(a0, b0, acc[0][0], 0, 0, 0);
        acc[0][1] = __builtin_amdgcn_mfma_f32_16x16x32_bf16(a0, b1, acc[0][1], 0, 0, 0);
        acc[1][0] = __builtin_amdgcn_mfma_f32_16x16x32_bf16(a1, b0, acc[1][0], 0, 0, 0);
        acc[1][1] = __builtin_amdgcn_mfma_f32_16x16x32_bf16(a1, b1, acc[1][1], 0, 0, 0);
    }
    const int gmb = m0 + wr + lq * 4;
    const int gnb = n0 + wc + lr;
#pragma unroll
    for (int mi = 0; mi < 2; mi++) {
#pragma unroll
        for (int ni = 0; ni < 2; ni++) {
            int gn = gnb + ni * 16;
            if (gn >= N) continue;
#pragma unroll
            for (int i = 0; i < 4; i++) {
                int gm = gmb + mi * 16 + i;
                size_t idx = (size_t)gm * N + gn;
                float v = acc[mi][ni][i];
                if constexpr (EP == 1) ((u16*)C)[idx] = f2b(tanhf(v));
            }
        }
    }
}

// ---------------- launch ----------------

extern "C" void kernel_launch(void* const* d_in, const int* in_sizes, int n_in,
                              void* d_out, int out_size, void* d_ws, size_t ws_size,
                              hipStream_t stream) {
    const float* x          = (const float*)d_in[0];
    const float* state      = (const float*)d_in[1];
    const float* ln1_w      = (const float*)d_in[2];
    const float* ln1_b      = (const float*)d_in[3];
    const float* ln2_w      = (const float*)d_in[4];
    const float* ln2_b      = (const float*)d_in[5];
    const float* maa_x      = (const float*)d_in[6];
    const float* maa_w1     = (const float*)d_in[7];
    const float* maa_w2     = (const float*)d_in[8];
    const float* maa_stack  = (const float*)d_in[9];
    const float* time_decay = (const float*)d_in[10];
    const float* td_w1      = (const float*)d_in[11];
    const float* td_w2      = (const float*)d_in[12];
    const float* u          = (const float*)d_in[13];
    const float* Wr         = (const float*)d_in[14];
    const float* Wk         = (const float*)d_in[15];
    const float* Wv         = (const float*)d_in[16];
    const float* Wg         = (const float*)d_in[17];
    const float* Wo         = (const float*)d_in[18];
    const float* gn_w       = (const float*)d_in[19];
    const float* gn_b       = (const float*)d_in[20];
    const float* ffn_k      = (const float*)d_in[21];
    const float* ffn_r      = (const float*)d_in[22];
    const float* Wfk        = (const float*)d_in[23];
    const float* Wfr        = (const float*)d_in[24];
    const float* Wfv        = (const float*)d_in[25];

    char* ws = (char*)d_ws;
    float* R0 = (float*)(ws);                        // xa -> wkv -> x1   (32 MiB f32)
    float* R1 = (float*)(ws + 33554432);             // Wdecay -> xc -> rr (32 MiB f32)
    u16*   R2 = (u16*)(ws + 67108864);               // mk/xm slot -> xk2 (16 MiB bf16)
    u16*   R3 = (u16*)(ws + 83886080);               // Rb -> xr2
    u16*   R4 = (u16*)(ws + 100663296);              // Kb -> kk
    u16*   R5 = (u16*)(ws + 117440512);              // Vb
    u16*   R6 = (u16*)(ws + 134217728);              // g -> ogg
    u16*   WB = (u16*)(ws + 150994944);              // weight bf16 slot (8 MiB)
    u16*   Hx = (u16*)(ws + 159383552);              // tanh(mk@w1)  NBL x 160
    u16*   Ht = (u16*)(ws + 160694272);              // tanh(xw@td1) NBL x 64
    u16*  WT1 = (u16*)(ws + 161218560);              // maa_w1^T  160 x 2048
    u16*  WT2 = (u16*)(ws + 161873920);              // maa_w2^T  5 x (2048 x 32)
    u16*  WT3 = (u16*)(ws + 162529280);              // td_w1^T   64 x 2048
    u16*  WT4 = (u16*)(ws + 162791424);              // td_w2^T   2048 x 64

    dim3 blk(256);
    dim3 blk512(512);
    dim3 g256(256);             // (4096/256) x (2048/128) = 256 tiles
    dim3 g128(16, 32);          // N=2048/128, M=4096/128 (small-K EPs)
    dim3 g160(3, 64), g64(1, 64);
    const int ncv = (E * E / 4) / 256;
    const int nel = NBLE / 1024;

    // small-weight transposes (to (N,K) bf16)
    k_transpose<<<(E * 160 + 255) / 256, blk, 0, stream>>>(maa_w1, WT1, E, 160);
    for (int f = 0; f < 5; f++)
        k_transpose<<<(32 * E + 255) / 256, blk, 0, stream>>>(maa_w2 + f * 32 * E, WT2 + f * E * 32, 32, E);
    k_transpose<<<(E * 64 + 255) / 256, blk, 0, stream>>>(td_w1, WT3, E, 64);
    k_transpose<<<(64 * E + 255) / 256, blk, 0, stream>>>(td_w2, WT4, 64, E);

    // time-mix front end
    k_ln<<<NBL, blk, 0, stream>>>(x, ln1_w, ln1_b, R0);                    // xa
    k_mk<<<nel, blk, 0, stream>>>(R0, state, maa_x, R2);                   // mk bf16
    k_gemm<1><<<g160, blk, 0, stream>>>(R2, E, WT1, Hx, NBL, 160, E);

    // decay chain (f=1: w)
    k_gemm128<2><<<g128, blk, 0, stream>>>(Hx + 1 * 32, 160, WT2 + 1 * E * 32, R2, 32,
                                           maa_stack + 1 * E, R0, state);
    k_gemm<1><<<g64, blk, 0, stream>>>(R2, E, WT3, Ht, NBL, 64, E);
    k_gemm128<3><<<g128, blk, 0, stream>>>(Ht, 64, WT4, R1, 64, time_decay, nullptr, nullptr);

    // k projection (f=0)
    k_gemm128<2><<<g128, blk, 0, stream>>>(Hx + 0 * 32, 160, WT2 + 0 * E * 32, R2, 32,
                                           maa_stack + 0 * E, R0, state);
    k_convert<<<ncv, blk, 0, stream>>>(Wk, WB, E * E);
    k_gemm256<9><<<g256, blk512, 0, stream>>>(R2, WB, R4, nullptr, nullptr);

    // v projection (f=2)
    k_gemm128<2><<<g128, blk, 0, stream>>>(Hx + 2 * 32, 160, WT2 + 2 * E * 32, R2, 32,
                                           maa_stack + 2 * E, R0, state);
    k_convert<<<ncv, blk, 0, stream>>>(Wv, WB, E * E);
    k_gemm256<9><<<g256, blk512, 0, stream>>>(R2, WB, R5, nullptr, nullptr);

    // g projection (f=4)
    k_gemm128<2><<<g128, blk, 0, stream>>>(Hx + 4 * 32, 160, WT2 + 4 * E * 32, R2, 32,
                                           maa_stack + 4 * E, R0, state);
    k_convert<<<ncv, blk, 0, stream>>>(Wg, WB, E * E);
    k_gemm256<10><<<g256, blk512, 0, stream>>>(R2, WB, R6, nullptr, nullptr);

    // r projection (f=3) — last use of xa (R0)
    k_gemm128<2><<<g128, blk, 0, stream>>>(Hx + 3 * 32, 160, WT2 + 3 * E * 32, R2, 32,
                                           maa_stack + 3 * E, R0, state);
    k_convert<<<ncv, blk, 0, stream>>>(Wr, WB, E * E);
    k_gemm256<9><<<g256, blk512, 0, stream>>>(R2, WB, R3, nullptr, nullptr);

    // sequential WKV scan -> R0 (wkv f32), then groupnorm * g -> ogg (R6 in place)
    k_scan<<<512, blk, 0, stream>>>(R3, R4, R5, R1, state, u, R0);
    k_gnorm<<<NBL * HHH / 4, blk, 0, stream>>>(R0, R6, gn_w, gn_b, R6);

    // output projection + residual -> x1 (R0; wkv dead)
    k_convert<<<ncv, blk, 0, stream>>>(Wo, WB, E * E);
    k_gemm256<5><<<g256, blk512, 0, stream>>>(R6, WB, R0, x, nullptr);

    // channel mix
    k_ln<<<NBL, blk, 0, stream>>>(R0, ln2_w, ln2_b, R1);                   // xc
    k_mix2<<<nel, blk, 0, stream>>>(R1, state, ffn_k, ffn_r, R2, R3);      // xk2, xr2
    k_convert<<<ncv, blk, 0, stream>>>(Wfk, WB, E * E);
    k_gemm256<7><<<g256, blk512, 0, stream>>>(R2, WB, R4, nullptr, nullptr);
    k_convert<<<ncv, blk, 0, stream>>>(Wfr, WB, E * E);
    k_gemm256<6><<<g256, blk512, 0, stream>>>(R3, WB, R1, nullptr, nullptr);
    k_convert<<<ncv, blk, 0, stream>>>(Wfv, WB, E * E);
    k_gemm256<8><<<g256, blk512, 0, stream>>>(R4, WB, (float*)d_out, R0, R1);
}